// Round 10
// baseline (93.326 us; speedup 1.0000x reference)
//
#include <hip/hip_runtime.h>
#include <math.h>

#define B_ 8
#define N_ 4096
// (1/sqrt(7)) * log2(e): Q pre-scale so logits are in base-2 domain (exp2 softmax)
#define SCALE2_ 0.54528747f

typedef __bf16 bf16x8 __attribute__((ext_vector_type(8)));
typedef float f32x4 __attribute__((ext_vector_type(4)));
typedef float f32x16 __attribute__((ext_vector_type(16)));
typedef unsigned short ushortx8 __attribute__((ext_vector_type(8)));
typedef unsigned short ushort;
typedef unsigned int uint;
typedef uint uint2v __attribute__((ext_vector_type(2)));

static __device__ __forceinline__ ushort f2bf(float f) {
  union { float f; unsigned u; } v; v.f = f;
  unsigned r = v.u + 0x7FFFu + ((v.u >> 16) & 1u);  // RNE
  return (ushort)(r >> 16);
}
static __device__ __forceinline__ uint pk2(float a, float b) {
  union { __bf16 h[2]; uint u; } v;
  v.h[0] = (__bf16)a; v.h[1] = (__bf16)b;
  return v.u;
}

// ---------------------------------------------------------------------------
// Kernel 1: projections (proven, ~13us). Qb (bf16, pre-scaled), Kb, Vt[b][o][n].
// ---------------------------------------------------------------------------
__global__ __launch_bounds__(256)
void proj_kernel(const float* __restrict__ x,
                 const float* __restrict__ Wq, const float* __restrict__ bq,
                 const float* __restrict__ Wk, const float* __restrict__ bk,
                 const float* __restrict__ Wv, const float* __restrict__ bv,
                 ushort* __restrict__ Qb, ushort* __restrict__ Kb,
                 ushort* __restrict__ Vt)
{
  __shared__ ushort sm[256][17];

  const int tid = threadIdx.x;
  const int gp  = (blockIdx.x << 8) + tid;
  const int b   = gp >> 12;
  const int y   = blockIdx.y;                // 0..11
  const int mat = y >> 2;                    // 0=Q 1=K 2=V
  const int o0  = (y & 3) << 4;
  const int n   = gp & 4095;

  const float* xb = x + ((size_t)b << 18) + n;
  float xr[64];
  #pragma unroll
  for (int c = 0; c < 64; ++c) xr[c] = xb[(size_t)c << 12];

  const float* W    = (mat == 0) ? Wq : (mat == 1) ? Wk : Wv;
  const float* bias = (mat == 0) ? bq : (mat == 1) ? bk : bv;

  float acc[16];
  #pragma unroll 1
  for (int j = 0; j < 16; ++j) {
    const float4* wr = (const float4*)(W + ((o0 + j) << 6));
    float a = bias[o0 + j];
    #pragma unroll
    for (int c4 = 0; c4 < 16; ++c4) {
      float4 w4 = wr[c4];
      a += w4.x * xr[4*c4] + w4.y * xr[4*c4+1] + w4.z * xr[4*c4+2] + w4.w * xr[4*c4+3];
    }
    acc[j] = a;
  }

  if (mat == 2) {
    #pragma unroll
    for (int j = 0; j < 16; ++j) sm[tid][j] = f2bf(acc[j]);
    __syncthreads();
    const int ol = tid >> 4;
    const int p0 = (tid & 15) << 4;
    uint pk[8];
    #pragma unroll
    for (int i = 0; i < 16; ++i) {
      ushort v = sm[p0 + i][ol];
      if (i & 1) pk[i >> 1] |= (uint)v << 16; else pk[i >> 1] = v;
    }
    const int nb = (blockIdx.x << 8) & 4095;
    ushort* dst = Vt + ((((size_t)b << 6) + o0 + ol) << 12) + nb + p0;
    *(ushortx8*)dst       = *(ushortx8*)&pk[0];
    *(ushortx8*)(dst + 8) = *(ushortx8*)&pk[4];
  } else {
    const float scl = (mat == 0) ? SCALE2_ : 1.0f;
    ushort* D = (mat == 0) ? Qb : Kb;
    __align__(16) ushort hv[16];
    #pragma unroll
    for (int j = 0; j < 16; ++j) hv[j] = f2bf(acc[j] * scl);
    const size_t base = ((size_t)gp << 6) + o0;
    *(ushortx8*)(D + base)     = *(const ushortx8*)&hv[0];
    *(ushortx8*)(D + base + 8) = *(const ushortx8*)&hv[8];
  }
}

// ---------------------------------------------------------------------------
// Kernel 2: flash attention, R9-proven block structure + GLOBAL KV-SPLIT.
// Each (b, 64q) tile handled by TWO blocks (kv halves of 2048) -> 1024 blocks
// -> 4 blocks/CU = 16 waves/CU (R9's 512-block grid capped occupancy at 18%).
// Max-free softmax (implicit m=0 shared by all partials) makes partials
// additive: block writes unnormalized O-sum + l; split 0 -> out, split 1 ->
// ws; combine kernel normalizes. Inside the block: proven 4-wave
// (2 q-groups x 2 kv-halves), reg-staged + padded LDS (0 conflicts),
// permlane32_swap EXCH, plain-bf16 S (absmax 0.047 proven).
// ---------------------------------------------------------------------------
__global__ __launch_bounds__(256, 4)
void flash_kernel(const ushort* __restrict__ Qb, const ushort* __restrict__ Kb,
                  const ushort* __restrict__ Vt, float* __restrict__ out,
                  float* __restrict__ Opart, float* __restrict__ Lp)
{
  __shared__ __align__(16) ushort KL[2][64][72];   // 18432 B
  __shared__ __align__(16) ushort VL[2][64][72];   // 18432 B

  const int tid  = threadIdx.x;
  const int lane = tid & 63;
  const int w    = tid >> 6;       // 0..3
  const int qg   = w >> 1;         // q-group
  const int kh   = w & 1;          // kv-half (within stage)
  const int r32  = lane & 31;
  const int h    = lane >> 5;      // 0..1
  const int h8   = h << 3;

  // 1024 blocks = 8 XCD x 128; XCD owns one batch. rem = qtile(6b) x split(1b)
  const int bidx = (blockIdx.x & 7) * 128 + (blockIdx.x >> 3);
  const int b   = bidx >> 7;
  const int rem = bidx & 127;
  const int qt  = rem >> 1;
  const int sp  = rem & 1;                    // global kv split
  const int qw  = (qt << 6) + (qg << 5);      // wave's 32-q base
  const int kvb = sp << 11;                   // 0 or 2048

  const ushort* KbB = Kb + ((size_t)b << 18);
  const ushort* VtB = Vt + ((size_t)b << 18);

  // Q B-frags: col(q)=lane&31, k(c)=16ks+8h+j
  bf16x8 qf[4];
  {
    const ushort* qp = Qb + ((((size_t)b << 12) + qw + r32) << 6) + h8;
    #pragma unroll
    for (int ks = 0; ks < 4; ++ks) qf[ks] = *(const bf16x8*)(qp + (ks << 4));
  }

  // staging: thread covers rows {srow, srow+32} of K and V (4 x 16B/stage)
  const int srow = tid >> 3;          // 0..31
  const int scg  = (tid & 7) << 3;    // 0..56

  ushortx8 rk0, rk1, rv0, rv1;
  #define STAGE_LOAD(c0) do { \
    rk0 = *(const ushortx8*)(KbB + (((size_t)((c0) + srow)) << 6) + scg); \
    rk1 = *(const ushortx8*)(KbB + (((size_t)((c0) + srow + 32)) << 6) + scg); \
    rv0 = *(const ushortx8*)(VtB + ((size_t)srow << 12) + (c0) + scg); \
    rv1 = *(const ushortx8*)(VtB + ((size_t)(srow + 32) << 12) + (c0) + scg); \
  } while (0)
  #define STAGE_WRITE(bf) do { \
    *(ushortx8*)&KL[bf][srow][scg]      = rk0; \
    *(ushortx8*)&KL[bf][srow + 32][scg] = rk1; \
    *(ushortx8*)&VL[bf][srow][scg]      = rv0; \
    *(ushortx8*)&VL[bf][srow + 32][scg] = rv1; \
  } while (0)

  STAGE_LOAD(kvb);
  STAGE_WRITE(0);

  const f32x16 Z = (f32x16)(0.0f);
  f32x16 acc0 = Z, acc1 = Z;
  float l_lane = 0.f;
  int cur = 0;

  const int krow = (kh << 5) + r32;   // wave's kv row for S
  const int vcb  = (kh << 5) + h8;    // wave's kv col base for PV

  for (int t = 0; t < 32; ++t) {
    __syncthreads();
    if (t < 31) STAGE_LOAD(kvb + ((t + 1) << 6));

    // ---- S^T = K * Q^T: 4 MFMAs over wave's 32-kv half ----
    bf16x8 kf0 = *(const bf16x8*)&KL[cur][krow][h8];
    f32x16 s = __builtin_amdgcn_mfma_f32_32x32x16_bf16(kf0, qf[0], Z, 0, 0, 0);
    #pragma unroll
    for (int ks = 1; ks < 4; ++ks) {
      bf16x8 kf = *(const bf16x8*)&KL[cur][krow][(ks << 4) + h8];
      s = __builtin_amdgcn_mfma_f32_32x32x16_bf16(kf, qf[ks], s, 0, 0, 0);
    }

    // ---- max-free softmax: p = exp2(s), per-lane l ----
    float rs = 0.f;
    #pragma unroll
    for (int i = 0; i < 16; ++i) {
      float p = __builtin_exp2f(s[i]);
      s[i] = p;
      rs += p;
    }
    l_lane += rs;

    // ---- P^T B-frags: 2 permlane32_swap per 8-val group (R9-proven) ----
    bf16x8 pb[2];
    #pragma unroll
    for (int c = 0; c < 2; ++c) {
      const int base = c << 3;
      uint plo0 = pk2(s[base+0], s[base+1]);
      uint plo1 = pk2(s[base+2], s[base+3]);
      uint phi0 = pk2(s[base+4], s[base+5]);
      uint phi1 = pk2(s[base+6], s[base+7]);
      uint2v r0 = __builtin_amdgcn_permlane32_swap(plo0, phi0, false, false);
      uint2v r1 = __builtin_amdgcn_permlane32_swap(plo1, phi1, false, false);
      union { uint u[4]; bf16x8 v; } f_;
      f_.u[0] = r0.x;
      f_.u[1] = r1.x;
      f_.u[2] = r0.y;
      f_.u[3] = r1.y;
      pb[c] = f_.v;
    }

    // ---- O^T += V^T * P^T over wave's 32 kv ----
    #pragma unroll
    for (int ks = 0; ks < 2; ++ks) {
      const int co = vcb + (ks << 4);
      bf16x8 v0 = *(const bf16x8*)&VL[cur][r32][co];
      acc0 = __builtin_amdgcn_mfma_f32_32x32x16_bf16(v0, pb[ks], acc0, 0, 0, 0);
      bf16x8 v1 = *(const bf16x8*)&VL[cur][32 + r32][co];
      acc1 = __builtin_amdgcn_mfma_f32_32x32x16_bf16(v1, pb[ks], acc1, 0, 0, 0);
    }

    if (t < 31) STAGE_WRITE(cur ^ 1);
    cur ^= 1;
  }

  // ---- merge in-block kv-half partials; write UNNORMALIZED partial + l ----
  float l_me = l_lane + __shfl_xor(l_lane, 32);

  __syncthreads();
  float* cmb = (float*)KL;   // [qg][lane][33] floats = 16896 B < 36864 B
  if (kh == 1) {
    float* p = cmb + ((qg << 6) + lane) * 33;
    #pragma unroll
    for (int i = 0; i < 16; ++i) { p[i] = acc0[i]; p[16 + i] = acc1[i]; }
    p[32] = l_me;
  }
  __syncthreads();
  if (kh == 0) {
    const float* p = cmb + ((qg << 6) + lane) * 33;
    const float ltot = l_me + p[32];
    float* dst = sp ? Opart : out;
    const size_t rowb = (((size_t)b << 12) + qw + r32) << 6;
    if (h == 0) Lp[(sp << 15) + (b << 12) + qw + r32] = ltot;
    #pragma unroll
    for (int g = 0; g < 4; ++g) {
      f32x4 o4;
      #pragma unroll
      for (int i = 0; i < 4; ++i)
        o4[i] = acc0[4*g + i] + p[4*g + i];
      *(f32x4*)(dst + rowb + (g << 3) + (h << 2)) = o4;
    }
    #pragma unroll
    for (int g = 0; g < 4; ++g) {
      f32x4 o4;
      #pragma unroll
      for (int i = 0; i < 4; ++i)
        o4[i] = acc1[4*g + i] + p[16 + 4*g + i];
      *(f32x4*)(dst + rowb + 32 + (g << 3) + (h << 2)) = o4;
    }
  }
  #undef STAGE_LOAD
  #undef STAGE_WRITE
}

// ---------------------------------------------------------------------------
// Kernel 3: combine the two kv-split partials: out = (O0 + O1) / (l0 + l1).
// 24MB traffic, memory-bound, ~5us.
// ---------------------------------------------------------------------------
__global__ __launch_bounds__(256)
void combine_kernel(float* __restrict__ out, const float* __restrict__ Opart,
                    const float* __restrict__ Lp)
{
  const int e   = ((blockIdx.x << 8) + threadIdx.x) << 2;
  const int row = e >> 6;
  const float inv = 1.0f / (Lp[row] + Lp[32768 + row]);
  f32x4 a = *(f32x4*)(out + e);
  f32x4 bb = *(const f32x4*)(Opart + e);
  #pragma unroll
  for (int i = 0; i < 4; ++i) a[i] = (a[i] + bb[i]) * inv;
  *(f32x4*)(out + e) = a;
}

extern "C" void kernel_launch(void* const* d_in, const int* in_sizes, int n_in,
                              void* d_out, int out_size, void* d_ws, size_t ws_size,
                              hipStream_t stream) {
  (void)in_sizes; (void)n_in; (void)out_size; (void)ws_size;
  const float* x  = (const float*)d_in[0];
  const float* Wq = (const float*)d_in[1];
  const float* bq = (const float*)d_in[2];
  const float* Wk = (const float*)d_in[3];
  const float* bk = (const float*)d_in[4];
  const float* Wv = (const float*)d_in[5];
  const float* bv = (const float*)d_in[6];
  float* out = (float*)d_out;

  const size_t SZ = (size_t)B_ * N_ * 64;          // 2,097,152
  ushort* Qb = (ushort*)d_ws;
  ushort* Kb = Qb + SZ;
  ushort* Vt = Kb + SZ;
  float*  Op = (float*)(Vt + SZ);                  // 8 MB partial (split 1)
  float*  Lp = Op + SZ;                            // 2 x 32768 floats

  proj_kernel<<<dim3(128, 12), dim3(256), 0, stream>>>(x, Wq, bq, Wk, bk, Wv, bv,
                                                       Qb, Kb, Vt);
  flash_kernel<<<dim3(1024), dim3(256), 0, stream>>>(Qb, Kb, Vt, out, Op, Lp);
  combine_kernel<<<dim3(2048), dim3(256), 0, stream>>>(out, Op, Lp);
}

// Round 11
// 90.860 us; speedup vs baseline: 1.0271x; 1.0271x over previous
//
#include <hip/hip_runtime.h>
#include <math.h>

#define B_ 8
#define N_ 4096
// (1/sqrt(7)) * log2(e): Q pre-scale so logits are in base-2 domain (exp2 softmax)
#define SCALE2_ 0.54528747f

typedef __bf16 bf16x8 __attribute__((ext_vector_type(8)));
typedef float f32x4 __attribute__((ext_vector_type(4)));
typedef float f32x16 __attribute__((ext_vector_type(16)));
typedef unsigned short ushortx8 __attribute__((ext_vector_type(8)));
typedef unsigned short ushort;
typedef unsigned int uint;
typedef uint uint2v __attribute__((ext_vector_type(2)));

static __device__ __forceinline__ ushort f2bf(float f) {
  union { float f; unsigned u; } v; v.f = f;
  unsigned r = v.u + 0x7FFFu + ((v.u >> 16) & 1u);  // RNE
  return (ushort)(r >> 16);
}
static __device__ __forceinline__ uint pk2(float a, float b) {
  union { __bf16 h[2]; uint u; } v;
  v.h[0] = (__bf16)a; v.h[1] = (__bf16)b;
  return v.u;
}

// ---------------------------------------------------------------------------
// Kernel 1: projections (proven, ~13us). Qb (bf16, pre-scaled), Kb, Vt[b][o][n].
// ---------------------------------------------------------------------------
__global__ __launch_bounds__(256)
void proj_kernel(const float* __restrict__ x,
                 const float* __restrict__ Wq, const float* __restrict__ bq,
                 const float* __restrict__ Wk, const float* __restrict__ bk,
                 const float* __restrict__ Wv, const float* __restrict__ bv,
                 ushort* __restrict__ Qb, ushort* __restrict__ Kb,
                 ushort* __restrict__ Vt)
{
  __shared__ ushort sm[256][17];

  const int tid = threadIdx.x;
  const int gp  = (blockIdx.x << 8) + tid;
  const int b   = gp >> 12;
  const int y   = blockIdx.y;                // 0..11
  const int mat = y >> 2;                    // 0=Q 1=K 2=V
  const int o0  = (y & 3) << 4;
  const int n   = gp & 4095;

  const float* xb = x + ((size_t)b << 18) + n;
  float xr[64];
  #pragma unroll
  for (int c = 0; c < 64; ++c) xr[c] = xb[(size_t)c << 12];

  const float* W    = (mat == 0) ? Wq : (mat == 1) ? Wk : Wv;
  const float* bias = (mat == 0) ? bq : (mat == 1) ? bk : bv;

  float acc[16];
  #pragma unroll 1
  for (int j = 0; j < 16; ++j) {
    const float4* wr = (const float4*)(W + ((o0 + j) << 6));
    float a = bias[o0 + j];
    #pragma unroll
    for (int c4 = 0; c4 < 16; ++c4) {
      float4 w4 = wr[c4];
      a += w4.x * xr[4*c4] + w4.y * xr[4*c4+1] + w4.z * xr[4*c4+2] + w4.w * xr[4*c4+3];
    }
    acc[j] = a;
  }

  if (mat == 2) {
    #pragma unroll
    for (int j = 0; j < 16; ++j) sm[tid][j] = f2bf(acc[j]);
    __syncthreads();
    const int ol = tid >> 4;
    const int p0 = (tid & 15) << 4;
    uint pk[8];
    #pragma unroll
    for (int i = 0; i < 16; ++i) {
      ushort v = sm[p0 + i][ol];
      if (i & 1) pk[i >> 1] |= (uint)v << 16; else pk[i >> 1] = v;
    }
    const int nb = (blockIdx.x << 8) & 4095;
    ushort* dst = Vt + ((((size_t)b << 6) + o0 + ol) << 12) + nb + p0;
    *(ushortx8*)dst       = *(ushortx8*)&pk[0];
    *(ushortx8*)(dst + 8) = *(ushortx8*)&pk[4];
  } else {
    const float scl = (mat == 0) ? SCALE2_ : 1.0f;
    ushort* D = (mat == 0) ? Qb : Kb;
    __align__(16) ushort hv[16];
    #pragma unroll
    for (int j = 0; j < 16; ++j) hv[j] = f2bf(acc[j] * scl);
    const size_t base = ((size_t)gp << 6) + o0;
    *(ushortx8*)(D + base)     = *(const ushortx8*)&hv[0];
    *(ushortx8*)(D + base + 8) = *(const ushortx8*)&hv[8];
  }
}

// ---------------------------------------------------------------------------
// Kernel 2: flash attention (R10-proven structure, + T5 setprio around MFMA
// clusters -- m191 regime: independent blocks per SIMD). GLOBAL KV-SPLIT:
// each (b, 64q) tile = 2 blocks (kv halves of 2048), 1024 blocks, 4 blk/CU.
// Max-free softmax (implicit m=0) -> partials additive; split 0 -> out,
// split 1 -> ws; combine normalizes. Inside: 4-wave (2 qg x 2 kh),
// reg-staged + padded LDS (0 conflicts), permlane32_swap EXCH, bf16 S.
// ---------------------------------------------------------------------------
__global__ __launch_bounds__(256, 4)
void flash_kernel(const ushort* __restrict__ Qb, const ushort* __restrict__ Kb,
                  const ushort* __restrict__ Vt, float* __restrict__ out,
                  float* __restrict__ Opart, float* __restrict__ Lp)
{
  __shared__ __align__(16) ushort KL[2][64][72];   // 18432 B
  __shared__ __align__(16) ushort VL[2][64][72];   // 18432 B

  const int tid  = threadIdx.x;
  const int lane = tid & 63;
  const int w    = tid >> 6;       // 0..3
  const int qg   = w >> 1;         // q-group
  const int kh   = w & 1;          // kv-half (within stage)
  const int r32  = lane & 31;
  const int h    = lane >> 5;      // 0..1
  const int h8   = h << 3;

  // 1024 blocks = 8 XCD x 128; XCD owns one batch. rem = qtile(6b) x split(1b)
  const int bidx = (blockIdx.x & 7) * 128 + (blockIdx.x >> 3);
  const int b   = bidx >> 7;
  const int rem = bidx & 127;
  const int qt  = rem >> 1;
  const int sp  = rem & 1;                    // global kv split
  const int qw  = (qt << 6) + (qg << 5);      // wave's 32-q base
  const int kvb = sp << 11;                   // 0 or 2048

  const ushort* KbB = Kb + ((size_t)b << 18);
  const ushort* VtB = Vt + ((size_t)b << 18);

  // Q B-frags: col(q)=lane&31, k(c)=16ks+8h+j
  bf16x8 qf[4];
  {
    const ushort* qp = Qb + ((((size_t)b << 12) + qw + r32) << 6) + h8;
    #pragma unroll
    for (int ks = 0; ks < 4; ++ks) qf[ks] = *(const bf16x8*)(qp + (ks << 4));
  }

  // staging: thread covers rows {srow, srow+32} of K and V (4 x 16B/stage)
  const int srow = tid >> 3;          // 0..31
  const int scg  = (tid & 7) << 3;    // 0..56

  ushortx8 rk0, rk1, rv0, rv1;
  #define STAGE_LOAD(c0) do { \
    rk0 = *(const ushortx8*)(KbB + (((size_t)((c0) + srow)) << 6) + scg); \
    rk1 = *(const ushortx8*)(KbB + (((size_t)((c0) + srow + 32)) << 6) + scg); \
    rv0 = *(const ushortx8*)(VtB + ((size_t)srow << 12) + (c0) + scg); \
    rv1 = *(const ushortx8*)(VtB + ((size_t)(srow + 32) << 12) + (c0) + scg); \
  } while (0)
  #define STAGE_WRITE(bf) do { \
    *(ushortx8*)&KL[bf][srow][scg]      = rk0; \
    *(ushortx8*)&KL[bf][srow + 32][scg] = rk1; \
    *(ushortx8*)&VL[bf][srow][scg]      = rv0; \
    *(ushortx8*)&VL[bf][srow + 32][scg] = rv1; \
  } while (0)

  STAGE_LOAD(kvb);
  STAGE_WRITE(0);

  const f32x16 Z = (f32x16)(0.0f);
  f32x16 acc0 = Z, acc1 = Z;
  float l_lane = 0.f;
  int cur = 0;

  const int krow = (kh << 5) + r32;   // wave's kv row for S
  const int vcb  = (kh << 5) + h8;    // wave's kv col base for PV

  for (int t = 0; t < 32; ++t) {
    __syncthreads();
    if (t < 31) STAGE_LOAD(kvb + ((t + 1) << 6));

    // ---- S^T = K * Q^T: 4 MFMAs over wave's 32-kv half ----
    __builtin_amdgcn_s_setprio(1);
    bf16x8 kf0 = *(const bf16x8*)&KL[cur][krow][h8];
    f32x16 s = __builtin_amdgcn_mfma_f32_32x32x16_bf16(kf0, qf[0], Z, 0, 0, 0);
    #pragma unroll
    for (int ks = 1; ks < 4; ++ks) {
      bf16x8 kf = *(const bf16x8*)&KL[cur][krow][(ks << 4) + h8];
      s = __builtin_amdgcn_mfma_f32_32x32x16_bf16(kf, qf[ks], s, 0, 0, 0);
    }
    __builtin_amdgcn_s_setprio(0);

    // ---- max-free softmax: p = exp2(s), per-lane l ----
    float rs = 0.f;
    #pragma unroll
    for (int i = 0; i < 16; ++i) {
      float p = __builtin_exp2f(s[i]);
      s[i] = p;
      rs += p;
    }
    l_lane += rs;

    // ---- P^T B-frags: 2 permlane32_swap per 8-val group (proven) ----
    bf16x8 pb[2];
    #pragma unroll
    for (int c = 0; c < 2; ++c) {
      const int base = c << 3;
      uint plo0 = pk2(s[base+0], s[base+1]);
      uint plo1 = pk2(s[base+2], s[base+3]);
      uint phi0 = pk2(s[base+4], s[base+5]);
      uint phi1 = pk2(s[base+6], s[base+7]);
      uint2v r0 = __builtin_amdgcn_permlane32_swap(plo0, phi0, false, false);
      uint2v r1 = __builtin_amdgcn_permlane32_swap(plo1, phi1, false, false);
      union { uint u[4]; bf16x8 v; } f_;
      f_.u[0] = r0.x;
      f_.u[1] = r1.x;
      f_.u[2] = r0.y;
      f_.u[3] = r1.y;
      pb[c] = f_.v;
    }

    // ---- O^T += V^T * P^T over wave's 32 kv ----
    __builtin_amdgcn_s_setprio(1);
    #pragma unroll
    for (int ks = 0; ks < 2; ++ks) {
      const int co = vcb + (ks << 4);
      bf16x8 v0 = *(const bf16x8*)&VL[cur][r32][co];
      acc0 = __builtin_amdgcn_mfma_f32_32x32x16_bf16(v0, pb[ks], acc0, 0, 0, 0);
      bf16x8 v1 = *(const bf16x8*)&VL[cur][32 + r32][co];
      acc1 = __builtin_amdgcn_mfma_f32_32x32x16_bf16(v1, pb[ks], acc1, 0, 0, 0);
    }
    __builtin_amdgcn_s_setprio(0);

    if (t < 31) STAGE_WRITE(cur ^ 1);
    cur ^= 1;
  }

  // ---- merge in-block kv-half partials; write UNNORMALIZED partial + l ----
  float l_me = l_lane + __shfl_xor(l_lane, 32);

  __syncthreads();
  float* cmb = (float*)KL;   // [qg][lane][33] floats = 16896 B < 36864 B
  if (kh == 1) {
    float* p = cmb + ((qg << 6) + lane) * 33;
    #pragma unroll
    for (int i = 0; i < 16; ++i) { p[i] = acc0[i]; p[16 + i] = acc1[i]; }
    p[32] = l_me;
  }
  __syncthreads();
  if (kh == 0) {
    const float* p = cmb + ((qg << 6) + lane) * 33;
    const float ltot = l_me + p[32];
    float* dst = sp ? Opart : out;
    const size_t rowb = (((size_t)b << 12) + qw + r32) << 6;
    if (h == 0) Lp[(sp << 15) + (b << 12) + qw + r32] = ltot;
    #pragma unroll
    for (int g = 0; g < 4; ++g) {
      f32x4 o4;
      #pragma unroll
      for (int i = 0; i < 4; ++i)
        o4[i] = acc0[4*g + i] + p[4*g + i];
      *(f32x4*)(dst + rowb + (g << 3) + (h << 2)) = o4;
    }
    #pragma unroll
    for (int g = 0; g < 4; ++g) {
      f32x4 o4;
      #pragma unroll
      for (int i = 0; i < 4; ++i)
        o4[i] = acc1[4*g + i] + p[16 + 4*g + i];
      *(f32x4*)(dst + rowb + 32 + (g << 3) + (h << 2)) = o4;
    }
  }
  #undef STAGE_LOAD
  #undef STAGE_WRITE
}

// ---------------------------------------------------------------------------
// Kernel 3: combine: out = (O0 + O1) / (l0 + l1). XCD-ALIGNED: block's XCD
// (= blockIdx%8 round-robin) matches the batch whose partials live in that
// XCD's L2 (flash for batch b ran entirely on XCD b). R10 ran this
// round-robin -> cross-die reads -> ~11us; aligned should be ~4-6us.
// ---------------------------------------------------------------------------
__global__ __launch_bounds__(256)
void combine_kernel(float* __restrict__ out, const float* __restrict__ Opart,
                    const float* __restrict__ Lp)
{
  // 2048 blocks = 8 batches x 256; batch = bidx>>8 must equal blockIdx&7
  const int bidx = ((blockIdx.x & 7) << 8) | (blockIdx.x >> 3);
  const int e   = ((bidx << 8) + threadIdx.x) << 2;
  const int row = e >> 6;
  const float inv = 1.0f / (Lp[row] + Lp[32768 + row]);
  f32x4 a = *(f32x4*)(out + e);
  f32x4 bb = *(const f32x4*)(Opart + e);
  #pragma unroll
  for (int i = 0; i < 4; ++i) a[i] = (a[i] + bb[i]) * inv;
  *(f32x4*)(out + e) = a;
}

extern "C" void kernel_launch(void* const* d_in, const int* in_sizes, int n_in,
                              void* d_out, int out_size, void* d_ws, size_t ws_size,
                              hipStream_t stream) {
  (void)in_sizes; (void)n_in; (void)out_size; (void)ws_size;
  const float* x  = (const float*)d_in[0];
  const float* Wq = (const float*)d_in[1];
  const float* bq = (const float*)d_in[2];
  const float* Wk = (const float*)d_in[3];
  const float* bk = (const float*)d_in[4];
  const float* Wv = (const float*)d_in[5];
  const float* bv = (const float*)d_in[6];
  float* out = (float*)d_out;

  const size_t SZ = (size_t)B_ * N_ * 64;          // 2,097,152
  ushort* Qb = (ushort*)d_ws;
  ushort* Kb = Qb + SZ;
  ushort* Vt = Kb + SZ;
  float*  Op = (float*)(Vt + SZ);                  // 8 MB partial (split 1)
  float*  Lp = Op + SZ;                            // 2 x 32768 floats

  proj_kernel<<<dim3(128, 12), dim3(256), 0, stream>>>(x, Wq, bq, Wk, bk, Wv, bv,
                                                       Qb, Kb, Vt);
  flash_kernel<<<dim3(1024), dim3(256), 0, stream>>>(Qb, Kb, Vt, out, Op, Lp);
  combine_kernel<<<dim3(2048), dim3(256), 0, stream>>>(out, Op, Lp);
}